// Round 2
// baseline (383.409 us; speedup 1.0000x reference)
//
#include <hip/hip_runtime.h>
#include <hip/hip_bf16.h>
#include <math.h>

// Problem constants
#define T_TOKENS 16384
#define HID      2048
#define NE       64     // experts
#define TOPK     8
// Tiling
#define TM       64     // tokens per block
#define BK       64     // k-chunk
#define LPAD     4      // LDS row pad (floats) -> row stride 68 breaks bank aliasing

__global__ __launch_bounds__(256) void router_kernel(
    const float* __restrict__ hidden,   // [T_TOKENS, HID]
    const float* __restrict__ weight,   // [NE, HID]
    float* __restrict__ out_logits,     // [T_TOKENS, NE]
    float* __restrict__ out_vals,       // [T_TOKENS, TOPK]
    float* __restrict__ out_idxf)       // [T_TOKENS, TOPK] (indices stored as float)
{
    // LDS: two f32 staging tiles for the GEMM, aliased by one f64 logit tile
    // for the epilogue (34816 B total; f64 tile needs 33280 B).
    __shared__ __align__(16) char smem[2 * TM * (BK + LPAD) * 4];
    float (*hs_s)[BK + LPAD] = reinterpret_cast<float(*)[BK + LPAD]>(smem);
    float (*w_s)[BK + LPAD]  = reinterpret_cast<float(*)[BK + LPAD]>(smem + TM * (BK + LPAD) * 4);
    double (*lg)[NE + 1]     = reinterpret_cast<double(*)[NE + 1]>(smem);

    const int tid  = threadIdx.x;
    const int tok0 = blockIdx.x * TM;

    const int ty = tid >> 4;   // 0..15 -> token group
    const int tx = tid & 15;   // 0..15 -> expert group

    // fp64 accumulation: ranking at the top-8 boundary needs better-than-f32
    // accuracy vs the numpy reference (f32 seq error ~5e-6 caused rank flips).
    double acc[4][4];
    #pragma unroll
    for (int i = 0; i < 4; ++i)
        #pragma unroll
        for (int j = 0; j < 4; ++j) acc[i][j] = 0.0;

    const int srow = tid >> 4;         // 0..15
    const int scol = (tid & 15) << 2;  // 0..60 step 4

    for (int k0 = 0; k0 < HID; k0 += BK) {
        // ---- stage hidden tile [TM][BK] and weight tile [NE][BK] (f32) ----
        #pragma unroll
        for (int r = 0; r < 4; ++r) {
            const int rr = srow + r * 16;  // 0..63
            const float4 hv = *(const float4*)&hidden[(size_t)(tok0 + rr) * HID + k0 + scol];
            *(float4*)&hs_s[rr][scol] = hv;
            const float4 wv = *(const float4*)&weight[(size_t)rr * HID + k0 + scol];
            *(float4*)&w_s[rr][scol] = wv;
        }
        __syncthreads();

        // ---- compute: 4 tokens x 4 experts per thread, f64 accumulate ----
        #pragma unroll 4
        for (int kk = 0; kk < BK; kk += 4) {
            float4 af[4], bf[4];
            #pragma unroll
            for (int i = 0; i < 4; ++i) af[i] = *(const float4*)&hs_s[ty * 4 + i][kk];
            #pragma unroll
            for (int j = 0; j < 4; ++j) bf[j] = *(const float4*)&w_s[tx * 4 + j][kk];
            double a[4][4], b[4][4];
            #pragma unroll
            for (int i = 0; i < 4; ++i) {
                a[i][0] = (double)af[i].x; a[i][1] = (double)af[i].y;
                a[i][2] = (double)af[i].z; a[i][3] = (double)af[i].w;
            }
            #pragma unroll
            for (int j = 0; j < 4; ++j) {
                b[j][0] = (double)bf[j].x; b[j][1] = (double)bf[j].y;
                b[j][2] = (double)bf[j].z; b[j][3] = (double)bf[j].w;
            }
            #pragma unroll
            for (int i = 0; i < 4; ++i)
                #pragma unroll
                for (int j = 0; j < 4; ++j) {
                    acc[i][j] = fma(a[i][0], b[j][0], acc[i][j]);
                    acc[i][j] = fma(a[i][1], b[j][1], acc[i][j]);
                    acc[i][j] = fma(a[i][2], b[j][2], acc[i][j]);
                    acc[i][j] = fma(a[i][3], b[j][3], acc[i][j]);
                }
        }
        __syncthreads();
    }

    // ---- write logits to global (coalesced float4, rounded from f64) ----
    #pragma unroll
    for (int i = 0; i < 4; ++i) {
        const int tok = tok0 + ty * 4 + i;
        float4 v = make_float4((float)acc[i][0], (float)acc[i][1],
                               (float)acc[i][2], (float)acc[i][3]);
        *(float4*)&out_logits[(size_t)tok * NE + tx * 4] = v;
    }

    // ---- stash f64 logit tile in LDS (aliases staging bufs; loop ended with
    //      __syncthreads so all compute reads are done) ----
    #pragma unroll
    for (int i = 0; i < 4; ++i)
        #pragma unroll
        for (int j = 0; j < 4; ++j)
            lg[ty * 4 + i][tx * 4 + j] = acc[i][j];
    __syncthreads();

    // ---- per-token top-8 + renormalized softmax over the selected 8 ----
    // Full softmax denominator cancels under renorm: vals = exp(l - lmax) / sum_top8.
    const int wave = tid >> 6;   // 0..3
    const int lane = tid & 63;   // expert id for this lane

    for (int tt = wave; tt < TM; tt += 4) {
        double cur = lg[tt][lane];
        double first = 0.0, s = 0.0, myv = 0.0;
        int myi = 0;
        #pragma unroll
        for (int i = 0; i < TOPK; ++i) {
            double mv = cur;
            int    mi = lane;
            #pragma unroll
            for (int off = 32; off; off >>= 1) {
                const double ov = __shfl_xor(mv, off);
                const int    oi = __shfl_xor(mi, off);
                if (ov > mv || (ov == mv && oi < mi)) { mv = ov; mi = oi; }
            }
            if (i == 0) first = mv;
            const double e = exp(mv - first);
            s += e;
            if (lane == i)  { myv = e; myi = mi; }
            if (lane == mi) cur = -INFINITY;   // remove winner
        }
        if (lane < TOPK) {
            const int tok = tok0 + tt;
            out_vals[(size_t)tok * TOPK + lane] = (float)(myv / s);
            out_idxf[(size_t)tok * TOPK + lane] = (float)myi;
        }
    }
}

extern "C" void kernel_launch(void* const* d_in, const int* in_sizes, int n_in,
                              void* d_out, int out_size, void* d_ws, size_t ws_size,
                              hipStream_t stream) {
    const float* hidden = (const float*)d_in[0];   // [16384, 2048] f32
    const float* weight = (const float*)d_in[1];   // [64, 2048] f32

    float* out        = (float*)d_out;
    float* out_logits = out;                                    // 16384*64
    float* out_vals   = out + (size_t)T_TOKENS * NE;            // 16384*8
    float* out_idxf   = out + (size_t)T_TOKENS * NE
                            + (size_t)T_TOKENS * TOPK;          // 16384*8

    dim3 grid(T_TOKENS / TM);
    dim3 block(256);
    hipLaunchKernelGGL(router_kernel, grid, block, 0, stream,
                       hidden, weight, out_logits, out_vals, out_idxf);
}